// Round 8
// baseline (226.389 us; speedup 1.0000x reference)
//
#include <hip/hip_runtime.h>

// Conv 3x3 VALID + ReLU over 262144 independent 16x8 fp32 images.
// Streaming op: 128 MiB in + 84 MiB out (~33us pure-traffic floor).
// R8 structure: NO LDS AT ALL. 8 lanes per image; lane L owns input rows
// 2L,2L+1 (4x float4 coalesced nt-load). Neighbor rows 2L+2,2L+3 arrive via
// __shfl_down(.,1) (DPP/bpermute, no LDS, no fences). Lane L computes output
// rows 2L,2L+1 (lane 7 computes nothing; its rows feed lane 6). Stores:
// 3x float4 per lane at 48-byte steps (16B aligned), full line coverage.
// Zero LDS -> no block-residency cap from LDS: ~32 waves/CU (2x round 5).
// nt hints kept: measured +10us vs plain (R5 vs R7 A/B).

#define BLOCK 256
#define NIMG_TOTAL (4096 * 64)

typedef float f32x4 __attribute__((ext_vector_type(4)));

__global__ __launch_bounds__(BLOCK) void conv3x3_relu_kernel(
    const float* __restrict__ x,
    const float* __restrict__ kern,
    float* __restrict__ out)
{
    const int tid   = threadIdx.x;
    const int lane8 = tid & 7;                          // sub-lane within image
    const long long img = (long long)blockIdx.x * (BLOCK / 8) + (tid >> 3);

    const float k00 = kern[0], k01 = kern[1], k02 = kern[2];
    const float k10 = kern[3], k11 = kern[4], k12 = kern[5];
    const float k20 = kern[6], k21 = kern[7], k22 = kern[8];

    // ---- load own 2 rows (16 floats = 4 x float4, coalesced) ----
    const f32x4* src = reinterpret_cast<const f32x4*>(x + img * 128) + lane8 * 4;
    f32x4 v0 = __builtin_nontemporal_load(&src[0]);
    f32x4 v1 = __builtin_nontemporal_load(&src[1]);
    f32x4 v2 = __builtin_nontemporal_load(&src[2]);
    f32x4 v3 = __builtin_nontemporal_load(&src[3]);

    float own0[8], own1[8], nbr0[8], nbr1[8];
    *reinterpret_cast<f32x4*>(&own0[0]) = v0;
    *reinterpret_cast<f32x4*>(&own0[4]) = v1;
    *reinterpret_cast<f32x4*>(&own1[0]) = v2;
    *reinterpret_cast<f32x4*>(&own1[4]) = v3;

    // ---- neighbor rows 2L+2, 2L+3 from lane+1 (unused garbage at lane8==7) ----
    #pragma unroll
    for (int j = 0; j < 8; ++j) nbr0[j] = __shfl_down(own0[j], 1);
    #pragma unroll
    for (int j = 0; j < 8; ++j) nbr1[j] = __shfl_down(own1[j], 1);

    // ---- compute output rows 2L (own0,own1,nbr0) and 2L+1 (own1,nbr0,nbr1) ----
    float a0[6], a1[6];
    #pragma unroll
    for (int c = 0; c < 6; ++c) {
        float s0 = own0[c] * k00 + own0[c + 1] * k01 + own0[c + 2] * k02
                 + own1[c] * k10 + own1[c + 1] * k11 + own1[c + 2] * k12
                 + nbr0[c] * k20 + nbr0[c + 1] * k21 + nbr0[c + 2] * k22;
        float s1 = own1[c] * k00 + own1[c + 1] * k01 + own1[c + 2] * k02
                 + nbr0[c] * k10 + nbr0[c + 1] * k11 + nbr0[c + 2] * k12
                 + nbr1[c] * k20 + nbr1[c + 1] * k21 + nbr1[c + 2] * k22;
        a0[c] = fmaxf(s0, 0.0f);
        a1[c] = fmaxf(s1, 0.0f);
    }

    // ---- store 12 floats (rows 2L,2L+1) at out + img*84 + L*12 ----
    if (lane8 < 7) {
        f32x4 w0, w1, w2;
        w0.x = a0[0]; w0.y = a0[1]; w0.z = a0[2]; w0.w = a0[3];
        w1.x = a0[4]; w1.y = a0[5]; w1.z = a1[0]; w1.w = a1[1];
        w2.x = a1[2]; w2.y = a1[3]; w2.z = a1[4]; w2.w = a1[5];
        f32x4* dst = reinterpret_cast<f32x4*>(out + img * 84 + lane8 * 12);
        __builtin_nontemporal_store(w0, &dst[0]);
        __builtin_nontemporal_store(w1, &dst[1]);
        __builtin_nontemporal_store(w2, &dst[2]);
    }
}

extern "C" void kernel_launch(void* const* d_in, const int* in_sizes, int n_in,
                              void* d_out, int out_size, void* d_ws, size_t ws_size,
                              hipStream_t stream) {
    const float* x    = (const float*)d_in[0];
    const float* kern = (const float*)d_in[1];
    float* out        = (float*)d_out;
    const int nblocks = NIMG_TOTAL / (BLOCK / 8);   // 8192 blocks, 32 images each
    conv3x3_relu_kernel<<<nblocks, BLOCK, 0, stream>>>(x, kern, out);
}

// Round 9
// 216.642 us; speedup vs baseline: 1.0450x; 1.0450x over previous
//
#include <hip/hip_runtime.h>

// Conv 3x3 VALID + ReLU over 262144 independent 16x8 fp32 images.
// Streaming op: 128 MiB in + 84 MiB out (~34us minimal-traffic floor).
// Structure = round 5 (best: kernel ~62us): wave-independent pipelines,
// private LDS slice, NO __syncthreads, one-shot 16-image chunk per wave,
// row split {4,3,4,3} (all LDS b128 <=2-way, free per m136).
// THIS ROUND'S single variable vs R5: loads are PLAIN (cached), stores stay
// nt. Discriminates "nt-load path cap ~3.5TB/s" (plain loads -> full-speed
// reads, win) vs "path capped regardless" (lose ~+10us via poison-eviction
// writebacks). R5/R7 flipped both sides at once and can't tell these apart.

#define BLOCK 256
#define IPW   16                 // images per wave (4 threads / image)
#define STRIDE 132               // floats per image in LDS (conflict-free w/ {4,3,4,3})
#define SLICE (IPW * STRIDE)     // 2112 floats = 8448 B per wave
#define NIMG_TOTAL (4096 * 64)

typedef float f32x4 __attribute__((ext_vector_type(4)));
typedef float f32x2 __attribute__((ext_vector_type(2)));

// wave-level LDS fence: all outstanding DS ops retired; no workgroup barrier.
#define FENCE_LDS() do { \
    asm volatile("s_waitcnt lgkmcnt(0)" ::: "memory"); \
    __builtin_amdgcn_wave_barrier(); \
} while (0)

__global__ __launch_bounds__(BLOCK, 4) void conv3x3_relu_kernel(
    const float* __restrict__ x,
    const float* __restrict__ kern,
    float* __restrict__ out)
{
    __shared__ float s[4 * SLICE];   // 33792 B -> 4 blocks/CU, 16 waves/CU

    const int tid  = threadIdx.x;
    const int wid  = tid >> 6;
    const int lane = tid & 63;
    float* sw = &s[wid * SLICE];     // wave-private slice

    const float k00 = kern[0], k01 = kern[1], k02 = kern[2];
    const float k10 = kern[3], k11 = kern[4], k12 = kern[5];
    const float k20 = kern[6], k21 = kern[7], k22 = kern[8];

    const long long imgbase = (long long)blockIdx.x * 64 + wid * IPW;

    // ---- phase 1: 16 images (8 KiB) coalesced PLAIN loads into regs ----
    const f32x4* src = reinterpret_cast<const f32x4*>(x) + imgbase * 32;
    f32x4 pf[8];   // fully unrolled -> static indices -> VGPRs
    #pragma unroll
    for (int k = 0; k < 8; ++k)
        pf[k] = src[k * 64 + lane];

    // ---- phase 2: stage into wave-private LDS (b128, conflict-free) ----
    #pragma unroll
    for (int k = 0; k < 8; ++k) {
        const int f  = k * 64 + lane;
        const int im = f >> 5;           // local image 0..15
        const int o4 = f & 31;
        *reinterpret_cast<f32x4*>(&sw[im * STRIDE + o4 * 4]) = pf[k];
    }
    FENCE_LDS();

    // ---- phase 3: compute; 4 threads/image, row split {4,3,4,3} ----
    const int img  = lane >> 2;
    const int tq   = lane & 3;
    const int rs   = tq * 4 - (tq >> 1);   // {0,4,7,11}
    const int rcnt = 4 - (tq & 1);         // {4,3,4,3}
    const float* ip = &sw[img * STRIDE];

    float w[3][8];
    float acc[4][6];
    *reinterpret_cast<f32x4*>(&w[0][0]) = *reinterpret_cast<const f32x4*>(ip + rs * 8);
    *reinterpret_cast<f32x4*>(&w[0][4]) = *reinterpret_cast<const f32x4*>(ip + rs * 8 + 4);
    *reinterpret_cast<f32x4*>(&w[1][0]) = *reinterpret_cast<const f32x4*>(ip + (rs + 1) * 8);
    *reinterpret_cast<f32x4*>(&w[1][4]) = *reinterpret_cast<const f32x4*>(ip + (rs + 1) * 8 + 4);
    #pragma unroll
    for (int rr = 0; rr < 4; ++rr) {
        if (rr < rcnt) {
            float* wn = w[(rr + 2) % 3];
            *reinterpret_cast<f32x4*>(&wn[0]) =
                *reinterpret_cast<const f32x4*>(ip + (rs + rr + 2) * 8);
            *reinterpret_cast<f32x4*>(&wn[4]) =
                *reinterpret_cast<const f32x4*>(ip + (rs + rr + 2) * 8 + 4);
            const float* r0 = w[rr % 3];
            const float* r1 = w[(rr + 1) % 3];
            const float* r2 = wn;
            #pragma unroll
            for (int c = 0; c < 6; ++c) {
                float a = r0[c] * k00 + r0[c + 1] * k01 + r0[c + 2] * k02
                        + r1[c] * k10 + r1[c + 1] * k11 + r1[c + 2] * k12
                        + r2[c] * k20 + r2[c + 1] * k21 + r2[c + 2] * k22;
                acc[rr][c] = fmaxf(a, 0.0f);
            }
        }
    }
    FENCE_LDS();   // all input reads retired before slice reuse

    // ---- phase 4: stage outputs (16 img * 84 floats, even offsets -> b64) ----
    #pragma unroll
    for (int rr = 0; rr < 4; ++rr) {
        if (rr < rcnt) {
            float* op = &sw[img * 84 + (rs + rr) * 6];
            f32x2 v01; v01.x = acc[rr][0]; v01.y = acc[rr][1];
            f32x2 v23; v23.x = acc[rr][2]; v23.y = acc[rr][3];
            f32x2 v45; v45.x = acc[rr][4]; v45.y = acc[rr][5];
            *reinterpret_cast<f32x2*>(op)     = v01;
            *reinterpret_cast<f32x2*>(op + 2) = v23;
            *reinterpret_cast<f32x2*>(op + 4) = v45;
        }
    }
    FENCE_LDS();

    // ---- phase 5: coalesced nt store (1344 floats = 336 float4 / wave) ----
    f32x4* dst = reinterpret_cast<f32x4*>(out + imgbase * 84);
    const f32x4* s4 = reinterpret_cast<const f32x4*>(sw);
    #pragma unroll
    for (int k = 0; k < 6; ++k) {
        const int f = k * 64 + lane;
        if (f < 336) __builtin_nontemporal_store(s4[f], &dst[f]);
    }
}

extern "C" void kernel_launch(void* const* d_in, const int* in_sizes, int n_in,
                              void* d_out, int out_size, void* d_ws, size_t ws_size,
                              hipStream_t stream) {
    const float* x    = (const float*)d_in[0];
    const float* kern = (const float*)d_in[1];
    float* out        = (float*)d_out;
    const int nblocks = NIMG_TOTAL / 64;   // 4096, one 64-image chunk each
    conv3x3_relu_kernel<<<nblocks, BLOCK, 0, stream>>>(x, kern, out);
}